// Round 1
// baseline (535.012 us; speedup 1.0000x reference)
//
#include <hip/hip_runtime.h>

#define B_ 64
#define NN 1024
#define FF 512

typedef float  fx4 __attribute__((ext_vector_type(4)));
typedef int    ix4 __attribute__((ext_vector_type(4)));
typedef unsigned int   ux4i __attribute__((ext_vector_type(4)));
typedef unsigned short us4  __attribute__((ext_vector_type(4)));
typedef short  sx8 __attribute__((ext_vector_type(8)));

static __device__ __forceinline__ unsigned short f2bf(float f){
    union { float f; unsigned u; } v; v.f = f;
    unsigned r = v.u + 0x7FFFu + ((v.u >> 16) & 1u);   // RTNE
    return (unsigned short)(r >> 16);
}
static __device__ __forceinline__ float bf2f(unsigned short h){
    union { unsigned u; float f; } v; v.u = ((unsigned)h) << 16;
    return v.f;
}

// ---------------- adj f32 -> bf16 ----------------
__global__ void k_cvt(const fx4* __restrict__ a, us4* __restrict__ o, int n4){
    int i = blockIdx.x * blockDim.x + threadIdx.x;
    int stride = gridDim.x * blockDim.x;
    for (; i < n4; i += stride){
        fx4 v = a[i];
        us4 r = { f2bf(v[0]), f2bf(v[1]), f2bf(v[2]), f2bf(v[3]) };
        o[i] = r;
    }
}

// ---------------- u1 = x @ We1  (f32 VALU), write bf16 transposed ----------------
__global__ __launch_bounds__(256) void k_xw1(
    const float* __restrict__ x, const float* __restrict__ We1,
    unsigned short* __restrict__ u1T){
    __shared__ float w1[FF][32];           // 64 KB, cols 30,31 zero
    int tid = threadIdx.x;
    int rt = blockIdx.x, b = blockIdx.y;
    for (int i = tid; i < FF*32; i += 256){
        int f = i >> 5, c = i & 31;
        w1[f][c] = (c < 30) ? We1[f*30 + c] : 0.f;
    }
    __syncthreads();
    int cg = tid & 7, rg = tid >> 3;       // 8 col-groups x 32 row-groups
    int row = rt*128 + rg*4;
    const float* xb = x + ((size_t)b*NN + row)*FF;
    float acc[4][4] = {};
    for (int f = 0; f < FF; f += 4){
        fx4 xv0 = *(const fx4*)(xb + 0*FF + f);
        fx4 xv1 = *(const fx4*)(xb + 1*FF + f);
        fx4 xv2 = *(const fx4*)(xb + 2*FF + f);
        fx4 xv3 = *(const fx4*)(xb + 3*FF + f);
        #pragma unroll
        for (int ff = 0; ff < 4; ff++){
            fx4 wv = *(const fx4*)&w1[f+ff][cg*4];
            #pragma unroll
            for (int c = 0; c < 4; c++){
                acc[0][c] += xv0[ff]*wv[c];
                acc[1][c] += xv1[ff]*wv[c];
                acc[2][c] += xv2[ff]*wv[c];
                acc[3][c] += xv3[ff]*wv[c];
            }
        }
    }
    #pragma unroll
    for (int c = 0; c < 4; c++){
        int col = cg*4 + c;
        us4 o = { f2bf(acc[0][c]), f2bf(acc[1][c]), f2bf(acc[2][c]), f2bf(acc[3][c]) };
        *(us4*)(u1T + ((size_t)b*32 + col)*NN + row) = o;
    }
}

// ---------------- out = act(adj @ U + bias), MFMA bf16 ----------------
// adjb: [B][1024][1024] bf16 ; uT: [B][32][1024] bf16 (U transposed) ;
// outT: [B][32][1024] bf16
__global__ __launch_bounds__(256) void k_adjmm(
    const unsigned short* __restrict__ adjb,
    const unsigned short* __restrict__ uT,
    const float* __restrict__ bias, int biasN, int relu,
    unsigned short* __restrict__ outT){
    __shared__ unsigned short uts[32*NN];  // 64 KB, XOR-swizzled
    int tid = threadIdx.x;
    int rt = blockIdx.x, b = blockIdx.y;
    // stage U^T (whole batch's 64 KB) with (c&7)<<4 byte-XOR swizzle
    const ux4i* src = (const ux4i*)(uT + (size_t)b*32*NN);
    #pragma unroll
    for (int i = 0; i < 16; i++){
        int j = tid + i*256;               // 16B-chunk index, c = j>>7
        int c = j >> 7;
        ux4i v = src[j];
        int dst = (j*16) ^ ((c & 7) << 4);
        *(ux4i*)((char*)uts + dst) = v;
    }
    __syncthreads();
    int w = tid >> 6, l = tid & 63;
    int lr = l & 15, lk = (l >> 4) * 8;
    const unsigned short* abase =
        adjb + (size_t)b*NN*NN + (size_t)(rt*128 + w*32 + lr)*NN + lk;
    int c0 = lr, c1 = 16 + lr;
    fx4 acc00 = {0,0,0,0}, acc01 = {0,0,0,0}, acc10 = {0,0,0,0}, acc11 = {0,0,0,0};
    #pragma unroll 4
    for (int kk = 0; kk < NN; kk += 32){
        sx8 a0 = *(const sx8*)(abase + kk);
        sx8 a1 = *(const sx8*)(abase + 16*NN + kk);
        int kb = (kk + lk) * 2;
        sx8 b0 = *(const sx8*)((const char*)uts + ((c0*2048 + kb) ^ ((c0 & 7) << 4)));
        sx8 b1 = *(const sx8*)((const char*)uts + ((c1*2048 + kb) ^ ((c1 & 7) << 4)));
        acc00 = __builtin_amdgcn_mfma_f32_16x16x32_bf16(a0, b0, acc00, 0, 0, 0);
        acc01 = __builtin_amdgcn_mfma_f32_16x16x32_bf16(a0, b1, acc01, 0, 0, 0);
        acc10 = __builtin_amdgcn_mfma_f32_16x16x32_bf16(a1, b0, acc10, 0, 0, 0);
        acc11 = __builtin_amdgcn_mfma_f32_16x16x32_bf16(a1, b1, acc11, 0, 0, 0);
    }
    float bias0 = 0.f, bias1 = 0.f;
    if (bias){
        if (c0 < biasN) bias0 = bias[c0];
        if (c1 < biasN) bias1 = bias[c1];
    }
    int lq = l >> 4;
    #pragma unroll
    for (int mt = 0; mt < 2; mt++){
        int row0 = rt*128 + w*32 + mt*16 + lq*4;
        fx4 am0 = mt ? acc10 : acc00;
        fx4 am1 = mt ? acc11 : acc01;
        #pragma unroll
        for (int ct = 0; ct < 2; ct++){
            fx4 a = ct ? am1 : am0;
            float bb = ct ? bias1 : bias0;
            int col = ct ? c1 : c0;
            us4 o;
            #pragma unroll
            for (int j = 0; j < 4; j++){
                float v = a[j] + bb;
                if (relu) v = fmaxf(v, 0.f);
                o[j] = f2bf(v);
            }
            *(us4*)(outT + ((size_t)b*32 + col)*NN + row0) = o;
        }
    }
}

// ---------------- tiny per-row transform: out = act(in @ W + bias) ----------------
template<int JI, int CO, bool RELU>
__global__ __launch_bounds__(256) void k_tiny(
    const unsigned short* __restrict__ inT, const float* __restrict__ W,
    const float* __restrict__ bias, unsigned short* __restrict__ outT){
    int n = blockIdx.x*256 + threadIdx.x;
    int b = blockIdx.y;
    const unsigned short* ip = inT + (size_t)b*32*NN + n;
    float in[JI];
    #pragma unroll
    for (int j = 0; j < JI; j++) in[j] = bf2f(ip[j*NN]);
    float acc[CO];
    #pragma unroll
    for (int c = 0; c < CO; c++) acc[c] = bias ? bias[c] : 0.f;
    #pragma unroll
    for (int j = 0; j < JI; j++){
        #pragma unroll
        for (int c = 0; c < CO; c++) acc[c] += in[j] * W[j*CO + c];
    }
    unsigned short* op = outT + (size_t)b*32*NN + n;
    #pragma unroll
    for (int c = 0; c < 32; c++){
        float v = (c < CO) ? (RELU ? fmaxf(acc[c], 0.f) : acc[c]) : 0.f;
        op[c*NN] = f2bf(v);
    }
}

// ---------------- dec = v2 @ Wd2 + bd2 ; softmax/sigmoid ; sampled ; log_probs ----
__global__ __launch_bounds__(256) void k_dec(
    const unsigned short* __restrict__ v2T,
    const float* __restrict__ Wd2, const float* __restrict__ bd2,
    const int* __restrict__ masks, const float* __restrict__ noise,
    float* __restrict__ dec, float* __restrict__ sampled, float* __restrict__ logp){
    __shared__ float red[4];
    int tid = threadIdx.x;
    int wid = tid >> 6, l = tid & 63;        // one wave per row
    int row = blockIdx.x*4 + wid;
    int b = row >> 10, n = row & (NN-1);
    const unsigned short* vp = v2T + (size_t)b*32*NN + n;
    float v2[30];
    #pragma unroll
    for (int j = 0; j < 30; j++) v2[j] = bf2f(vp[j*NN]);
    int c0 = l*8;
    float d[8];
    {
        fx4 b0 = *(const fx4*)(bd2 + c0);
        fx4 b1 = *(const fx4*)(bd2 + c0 + 4);
        #pragma unroll
        for (int i = 0; i < 4; i++){ d[i] = b0[i]; d[4+i] = b1[i]; }
    }
    #pragma unroll
    for (int j = 0; j < 30; j++){
        fx4 w0 = *(const fx4*)(Wd2 + j*FF + c0);
        fx4 w1 = *(const fx4*)(Wd2 + j*FF + c0 + 4);
        #pragma unroll
        for (int i = 0; i < 4; i++){ d[i] += v2[j]*w0[i]; d[4+i] += v2[j]*w1[i]; }
    }
    float act[8];
    if (l < 4){  // cols 0..31 -> softmax across 4 lanes (shuffles stay in-group)
        float mx = d[0];
        #pragma unroll
        for (int i = 1; i < 8; i++) mx = fmaxf(mx, d[i]);
        mx = fmaxf(mx, __shfl_xor(mx, 1, 4));
        mx = fmaxf(mx, __shfl_xor(mx, 2, 4));
        float s = 0.f;
        #pragma unroll
        for (int i = 0; i < 8; i++){ act[i] = __expf(d[i] - mx); s += act[i]; }
        s += __shfl_xor(s, 1, 4);
        s += __shfl_xor(s, 2, 4);
        float inv = 1.f / s;
        #pragma unroll
        for (int i = 0; i < 8; i++) act[i] *= inv;
    } else {     // sigmoid
        #pragma unroll
        for (int i = 0; i < 8; i++) act[i] = 1.f / (1.f + __expf(-d[i]));
    }
    size_t base = ((size_t)b*NN + n)*FF + c0;
    ix4 m0 = *(const ix4*)(masks + base);
    ix4 m1 = *(const ix4*)(masks + base + 4);
    fx4 z0 = *(const fx4*)(noise + base);
    fx4 z1 = *(const fx4*)(noise + base + 4);
    const float LPC = 2.9930844722234733f;   // -log(sigma) - 0.5*log(2*pi)
    float lp = 0.f;
    fx4 sm0, sm1, dd0, dd1;
    #pragma unroll
    for (int i = 0; i < 4; i++){
        float mi0 = (float)m0[i], zi0 = z0[i];
        float mi1 = (float)m1[i], zi1 = z1[i];
        dd0[i] = d[i];        dd1[i] = d[4+i];
        sm0[i] = act[i]   + mi0*(0.02f*zi0);
        sm1[i] = act[4+i] + mi1*(0.02f*zi1);
        lp += mi0*(LPC - 0.5f*zi0*zi0) + mi1*(LPC - 0.5f*zi1*zi1);
    }
    *(fx4*)(dec + base)       = dd0;
    *(fx4*)(dec + base + 4)   = dd1;
    *(fx4*)(sampled + base)     = sm0;
    *(fx4*)(sampled + base + 4) = sm1;
    #pragma unroll
    for (int off = 32; off > 0; off >>= 1) lp += __shfl_xor(lp, off);
    if (l == 0) red[wid] = lp;
    __syncthreads();
    if (tid == 0) atomicAdd(logp + b, red[0] + red[1] + red[2] + red[3]);
}

extern "C" void kernel_launch(void* const* d_in, const int* in_sizes, int n_in,
                              void* d_out, int out_size, void* d_ws, size_t ws_size,
                              hipStream_t stream){
    const float* x     = (const float*)d_in[0];
    const float* adj   = (const float*)d_in[1];
    const int*   masks = (const int*)  d_in[2];
    const float* noise = (const float*)d_in[3];
    const float* We1   = (const float*)d_in[4];
    const float* be1   = (const float*)d_in[5];
    const float* We2   = (const float*)d_in[6];
    const float* be2   = (const float*)d_in[7];
    const float* Wd1   = (const float*)d_in[8];
    const float* bd1   = (const float*)d_in[9];
    const float* Wd2   = (const float*)d_in[10];
    const float* bd2   = (const float*)d_in[11];

    float* dec     = (float*)d_out;
    float* sampled = dec + (size_t)B_*NN*FF;
    float* logp    = sampled + (size_t)B_*NN*FF;
    // dec region (exactly 134,217,728 B) doubles as bf16-adj scratch until k_dec
    unsigned short* adjb = (unsigned short*)d_out;
    unsigned short* bufA = (unsigned short*)d_ws;              // 4 MB each
    unsigned short* bufB = bufA + (size_t)B_*32*NN;

    hipMemsetAsync(logp, 0, B_*sizeof(float), stream);
    k_cvt<<<2048, 256, 0, stream>>>((const fx4*)adj, (us4*)adjb, B_*NN*NN/4);
    k_xw1<<<dim3(8, B_), 256, 0, stream>>>(x, We1, bufA);                       // u1
    k_adjmm<<<dim3(8, B_), 256, 0, stream>>>(adjb, bufA, be1, 30, 1, bufB);     // h1
    k_tiny<30,18,false><<<dim3(4, B_), 256, 0, stream>>>(bufB, We2, nullptr, bufA); // u2
    k_adjmm<<<dim3(8, B_), 256, 0, stream>>>(adjb, bufA, be2, 18, 0, bufB);     // enc
    k_adjmm<<<dim3(8, B_), 256, 0, stream>>>(adjb, bufB, nullptr, 0, 0, bufA);  // v1
    k_tiny<18,30,true><<<dim3(4, B_), 256, 0, stream>>>(bufA, Wd1, bd1, bufB);  // h2
    k_adjmm<<<dim3(8, B_), 256, 0, stream>>>(adjb, bufB, nullptr, 0, 0, bufA);  // v2
    k_dec<<<B_*NN/4, 256, 0, stream>>>(bufA, Wd2, bd2, masks, noise, dec, sampled, logp);
}

// Round 2
// 414.066 us; speedup vs baseline: 1.2921x; 1.2921x over previous
//
#include <hip/hip_runtime.h>

#define B_ 64
#define NN 1024
#define FF 512

typedef float  fx4 __attribute__((ext_vector_type(4)));
typedef int    ix4 __attribute__((ext_vector_type(4)));
typedef unsigned int   ux4i __attribute__((ext_vector_type(4)));
typedef unsigned short us4  __attribute__((ext_vector_type(4)));
typedef short  sx8 __attribute__((ext_vector_type(8)));

static __device__ __forceinline__ unsigned short f2bf(float f){
    union { float f; unsigned u; } v; v.f = f;
    unsigned r = v.u + 0x7FFFu + ((v.u >> 16) & 1u);   // RTNE
    return (unsigned short)(r >> 16);
}
static __device__ __forceinline__ float bf2f(unsigned short h){
    union { unsigned u; float f; } v; v.u = ((unsigned)h) << 16;
    return v.f;
}

// ---------------- u1 = x @ We1  (f32 VALU), write bf16 transposed ----------------
__global__ __launch_bounds__(256) void k_xw1(
    const float* __restrict__ x, const float* __restrict__ We1,
    unsigned short* __restrict__ u1T){
    __shared__ float w1[FF][32];           // 64 KB, cols 30,31 zero
    int tid = threadIdx.x;
    int rt = blockIdx.x, b = blockIdx.y;
    for (int i = tid; i < FF*32; i += 256){
        int f = i >> 5, c = i & 31;
        w1[f][c] = (c < 30) ? We1[f*30 + c] : 0.f;
    }
    __syncthreads();
    int cg = tid & 7, rg = tid >> 3;       // 8 col-groups x 32 row-groups
    int row = rt*128 + rg*4;
    const float* xb = x + ((size_t)b*NN + row)*FF;
    float acc[4][4] = {};
    for (int f = 0; f < FF; f += 4){
        fx4 xv0 = *(const fx4*)(xb + 0*FF + f);
        fx4 xv1 = *(const fx4*)(xb + 1*FF + f);
        fx4 xv2 = *(const fx4*)(xb + 2*FF + f);
        fx4 xv3 = *(const fx4*)(xb + 3*FF + f);
        #pragma unroll
        for (int ff = 0; ff < 4; ff++){
            fx4 wv = *(const fx4*)&w1[f+ff][cg*4];
            #pragma unroll
            for (int c = 0; c < 4; c++){
                acc[0][c] += xv0[ff]*wv[c];
                acc[1][c] += xv1[ff]*wv[c];
                acc[2][c] += xv2[ff]*wv[c];
                acc[3][c] += xv3[ff]*wv[c];
            }
        }
    }
    #pragma unroll
    for (int c = 0; c < 4; c++){
        int col = cg*4 + c;
        us4 o = { f2bf(acc[0][c]), f2bf(acc[1][c]), f2bf(acc[2][c]), f2bf(acc[3][c]) };
        *(us4*)(u1T + ((size_t)b*32 + col)*NN + row) = o;
    }
}

// ---------------- out = act(adj @ U + bias), MFMA bf16 ----------------
// CVT: A read from f32 adj, converted in-register, bf16 fragment stored to adjb.
// RM : output written row-major [B][N][32] (for k_dec) instead of [B][32][N].
template<int CVT, int RM>
__global__ __launch_bounds__(256) void k_adjmm(
    const float* __restrict__ adjf,
    const unsigned short* __restrict__ adjb_in,
    unsigned short* __restrict__ adjb_out,
    const unsigned short* __restrict__ uT,
    const float* __restrict__ bias, int biasN, int relu,
    unsigned short* __restrict__ outT){
    __shared__ unsigned short uts[32*NN];  // 64 KB, XOR-swizzled
    int tid = threadIdx.x;
    int rt = blockIdx.x, b = blockIdx.y;
    // stage U^T (whole batch's 64 KB) with (c&7)<<4 byte-XOR swizzle
    const ux4i* src = (const ux4i*)(uT + (size_t)b*32*NN);
    #pragma unroll
    for (int i = 0; i < 16; i++){
        int j = tid + i*256;               // 16B-chunk index, c = j>>7
        int c = j >> 7;
        ux4i v = src[j];
        int dst = (j*16) ^ ((c & 7) << 4);
        *(ux4i*)((char*)uts + dst) = v;
    }
    __syncthreads();
    int w = tid >> 6, l = tid & 63;
    int lr = l & 15, lk = (l >> 4) * 8;
    size_t aoff = (size_t)b*NN*NN + (size_t)(rt*128 + w*32 + lr)*NN + lk;
    int c0 = lr, c1 = 16 + lr;
    fx4 acc00 = {0,0,0,0}, acc01 = {0,0,0,0}, acc10 = {0,0,0,0}, acc11 = {0,0,0,0};
    #pragma unroll 4
    for (int kk = 0; kk < NN; kk += 32){
        sx8 a0, a1;
        if (CVT){
            fx4 v00 = *(const fx4*)(adjf + aoff + kk);
            fx4 v01 = *(const fx4*)(adjf + aoff + kk + 4);
            fx4 v10 = *(const fx4*)(adjf + aoff + 16*NN + kk);
            fx4 v11 = *(const fx4*)(adjf + aoff + 16*NN + kk + 4);
            #pragma unroll
            for (int t = 0; t < 4; t++){
                a0[t] = (short)f2bf(v00[t]); a0[4+t] = (short)f2bf(v01[t]);
                a1[t] = (short)f2bf(v10[t]); a1[4+t] = (short)f2bf(v11[t]);
            }
            *(sx8*)(adjb_out + aoff + kk) = a0;
            *(sx8*)(adjb_out + aoff + 16*NN + kk) = a1;
        } else {
            a0 = *(const sx8*)(adjb_in + aoff + kk);
            a1 = *(const sx8*)(adjb_in + aoff + 16*NN + kk);
        }
        int kb = (kk + lk) * 2;
        sx8 b0 = *(const sx8*)((const char*)uts + ((c0*2048 + kb) ^ ((c0 & 7) << 4)));
        sx8 b1 = *(const sx8*)((const char*)uts + ((c1*2048 + kb) ^ ((c1 & 7) << 4)));
        acc00 = __builtin_amdgcn_mfma_f32_16x16x32_bf16(a0, b0, acc00, 0, 0, 0);
        acc01 = __builtin_amdgcn_mfma_f32_16x16x32_bf16(a0, b1, acc01, 0, 0, 0);
        acc10 = __builtin_amdgcn_mfma_f32_16x16x32_bf16(a1, b0, acc10, 0, 0, 0);
        acc11 = __builtin_amdgcn_mfma_f32_16x16x32_bf16(a1, b1, acc11, 0, 0, 0);
    }
    float bias0 = 0.f, bias1 = 0.f;
    if (bias){
        if (c0 < biasN) bias0 = bias[c0];
        if (c1 < biasN) bias1 = bias[c1];
    }
    int lq = l >> 4;
    #pragma unroll
    for (int mt = 0; mt < 2; mt++){
        int row0 = rt*128 + w*32 + mt*16 + lq*4;
        fx4 am0 = mt ? acc10 : acc00;
        fx4 am1 = mt ? acc11 : acc01;
        #pragma unroll
        for (int ct = 0; ct < 2; ct++){
            fx4 a = ct ? am1 : am0;
            float bb = ct ? bias1 : bias0;
            int col = ct ? c1 : c0;
            us4 o;
            #pragma unroll
            for (int j = 0; j < 4; j++){
                float v = a[j] + bb;
                if (relu) v = fmaxf(v, 0.f);
                o[j] = f2bf(v);
            }
            if (RM){
                #pragma unroll
                for (int j = 0; j < 4; j++)
                    outT[((size_t)b*NN + row0 + j)*32 + col] = o[j];
            } else {
                *(us4*)(outT + ((size_t)b*32 + col)*NN + row0) = o;
            }
        }
    }
}

// ---------------- tiny per-row transform: out = act(in @ W + bias) ----------------
template<int JI, int CO, bool RELU>
__global__ __launch_bounds__(256) void k_tiny(
    const unsigned short* __restrict__ inT, const float* __restrict__ W,
    const float* __restrict__ bias, unsigned short* __restrict__ outT){
    int n = blockIdx.x*256 + threadIdx.x;
    int b = blockIdx.y;
    const unsigned short* ip = inT + (size_t)b*32*NN + n;
    float in[JI];
    #pragma unroll
    for (int j = 0; j < JI; j++) in[j] = bf2f(ip[j*NN]);
    float acc[CO];
    #pragma unroll
    for (int c = 0; c < CO; c++) acc[c] = bias ? bias[c] : 0.f;
    #pragma unroll
    for (int j = 0; j < JI; j++){
        #pragma unroll
        for (int c = 0; c < CO; c++) acc[c] += in[j] * W[j*CO + c];
    }
    unsigned short* op = outT + (size_t)b*32*NN + n;
    #pragma unroll
    for (int c = 0; c < 32; c++){
        float v = (c < CO) ? (RELU ? fmaxf(acc[c], 0.f) : acc[c]) : 0.f;
        op[c*NN] = f2bf(v);
    }
}

// ---------------- dec = v2 @ Wd2 + bd2 ; softmax/sigmoid ; sampled ; log_probs ----
// v2R: [B*N][32] bf16 row-major. Wd2 staged in LDS (f32, XOR-swizzled bit4^=bit7).
__global__ __launch_bounds__(512, 4) void k_dec(
    const unsigned short* __restrict__ v2R,
    const float* __restrict__ Wd2, const float* __restrict__ bd2,
    const int* __restrict__ masks, const float* __restrict__ noise,
    float* __restrict__ dec, float* __restrict__ sampled, float* __restrict__ logp){
    __shared__ float wls[30*FF];           // 61440 B
    __shared__ float red[8];
    int tid = threadIdx.x;
    for (int i = tid; i < 30*FF/4; i += 512){
        fx4 v = ((const fx4*)Wd2)[i];
        int byte = i*16;
        byte ^= ((byte >> 7) & 1) << 4;
        *(fx4*)((char*)wls + byte) = v;
    }
    int wid = tid >> 6, l = tid & 63, c0 = l*8;
    int rowbase = blockIdx.x*32 + wid*4;   // 32 rows per block, same b for all
    int b = rowbase >> 10;
    fx4 bb0 = *(const fx4*)(bd2 + c0);
    fx4 bb1 = *(const fx4*)(bd2 + c0 + 4);
    const float LPC = 2.9930844722234733f; // -log(sigma) - 0.5*log(2*pi)
    float lpacc = 0.f;
    __syncthreads();
    #pragma unroll
    for (int it = 0; it < 2; it++){
        int r0 = rowbase + it*2;           // global row (= b*NN + n)
        int r1 = r0 + 1;
        // packed v2 rows (32 bf16 = 64 B each)
        ux4i p00 = *(const ux4i*)(v2R + (size_t)r0*32);
        ux4i p01 = *(const ux4i*)(v2R + (size_t)r0*32 + 8);
        ux4i p02 = *(const ux4i*)(v2R + (size_t)r0*32 + 16);
        ux4i p03 = *(const ux4i*)(v2R + (size_t)r0*32 + 24);
        ux4i p10 = *(const ux4i*)(v2R + (size_t)r1*32);
        ux4i p11 = *(const ux4i*)(v2R + (size_t)r1*32 + 8);
        ux4i p12 = *(const ux4i*)(v2R + (size_t)r1*32 + 16);
        ux4i p13 = *(const ux4i*)(v2R + (size_t)r1*32 + 24);
        size_t base0 = (size_t)r0*FF + c0;
        size_t base1 = (size_t)r1*FF + c0;
        // prefetch streaming operands
        ix4 m00 = *(const ix4*)(masks + base0);
        ix4 m01 = *(const ix4*)(masks + base0 + 4);
        ix4 m10 = *(const ix4*)(masks + base1);
        ix4 m11 = *(const ix4*)(masks + base1 + 4);
        fx4 z00 = *(const fx4*)(noise + base0);
        fx4 z01 = *(const fx4*)(noise + base0 + 4);
        fx4 z10 = *(const fx4*)(noise + base1);
        fx4 z11 = *(const fx4*)(noise + base1 + 4);
        float d0[8], d1[8];
        #pragma unroll
        for (int i = 0; i < 4; i++){
            d0[i] = bb0[i]; d0[4+i] = bb1[i];
            d1[i] = bb0[i]; d1[4+i] = bb1[i];
        }
        #pragma unroll
        for (int j = 0; j < 30; j++){
            int off = j*2048 + l*32;
            int o0 = off ^ ((off >> 7 & 1) << 4);
            int off1 = off + 16;
            int o1 = off1 ^ ((off1 >> 7 & 1) << 4);
            fx4 w0 = *(const fx4*)((const char*)wls + o0);
            fx4 w1 = *(const fx4*)((const char*)wls + o1);
            unsigned pd0 = ((const unsigned*)&p00)[0]; // indexed below instead
            (void)pd0;
            unsigned q0, q1;
            {   // extract packed dword j>>1 of each row
                const unsigned* pr0 = (const unsigned*)&p00;
                const unsigned* pr1 = (const unsigned*)&p10;
                int di = j >> 1;
                // p00..p03 are contiguous locals; index via switch-free math:
                q0 = (di < 4) ? ((const unsigned*)&p00)[di] :
                     (di < 8) ? ((const unsigned*)&p01)[di-4] :
                     (di <12) ? ((const unsigned*)&p02)[di-8] :
                                ((const unsigned*)&p03)[di-12];
                q1 = (di < 4) ? ((const unsigned*)&p10)[di] :
                     (di < 8) ? ((const unsigned*)&p11)[di-4] :
                     (di <12) ? ((const unsigned*)&p12)[di-8] :
                                ((const unsigned*)&p13)[di-12];
                (void)pr0; (void)pr1;
            }
            union { unsigned u; float f; } a0, a1;
            a0.u = (j & 1) ? (q0 & 0xFFFF0000u) : (q0 << 16);
            a1.u = (j & 1) ? (q1 & 0xFFFF0000u) : (q1 << 16);
            #pragma unroll
            for (int i = 0; i < 4; i++){
                d0[i]   += a0.f * w0[i];
                d0[4+i] += a0.f * w1[i];
                d1[i]   += a1.f * w0[i];
                d1[4+i] += a1.f * w1[i];
            }
        }
        // activations
        float act0[8], act1[8];
        if (l < 4){
            float mx0 = d0[0], mx1 = d1[0];
            #pragma unroll
            for (int i = 1; i < 8; i++){ mx0 = fmaxf(mx0, d0[i]); mx1 = fmaxf(mx1, d1[i]); }
            mx0 = fmaxf(mx0, __shfl_xor(mx0, 1, 4)); mx0 = fmaxf(mx0, __shfl_xor(mx0, 2, 4));
            mx1 = fmaxf(mx1, __shfl_xor(mx1, 1, 4)); mx1 = fmaxf(mx1, __shfl_xor(mx1, 2, 4));
            float s0 = 0.f, s1 = 0.f;
            #pragma unroll
            for (int i = 0; i < 8; i++){
                act0[i] = __expf(d0[i] - mx0); s0 += act0[i];
                act1[i] = __expf(d1[i] - mx1); s1 += act1[i];
            }
            s0 += __shfl_xor(s0, 1, 4); s0 += __shfl_xor(s0, 2, 4);
            s1 += __shfl_xor(s1, 1, 4); s1 += __shfl_xor(s1, 2, 4);
            float i0 = 1.f/s0, i1 = 1.f/s1;
            #pragma unroll
            for (int i = 0; i < 8; i++){ act0[i] *= i0; act1[i] *= i1; }
        } else {
            #pragma unroll
            for (int i = 0; i < 8; i++){
                act0[i] = 1.f / (1.f + __expf(-d0[i]));
                act1[i] = 1.f / (1.f + __expf(-d1[i]));
            }
        }
        fx4 dd, sm;
        #pragma unroll
        for (int i = 0; i < 4; i++){ dd[i] = d0[i]; }
        *(fx4*)(dec + base0) = dd;
        #pragma unroll
        for (int i = 0; i < 4; i++){ dd[i] = d0[4+i]; }
        *(fx4*)(dec + base0 + 4) = dd;
        #pragma unroll
        for (int i = 0; i < 4; i++){ dd[i] = d1[i]; }
        *(fx4*)(dec + base1) = dd;
        #pragma unroll
        for (int i = 0; i < 4; i++){ dd[i] = d1[4+i]; }
        *(fx4*)(dec + base1 + 4) = dd;
        #pragma unroll
        for (int i = 0; i < 4; i++){
            float mi = (float)m00[i], zi = z00[i];
            sm[i] = act0[i] + mi*(0.02f*zi);
            lpacc += mi*(LPC - 0.5f*zi*zi);
        }
        *(fx4*)(sampled + base0) = sm;
        #pragma unroll
        for (int i = 0; i < 4; i++){
            float mi = (float)m01[i], zi = z01[i];
            sm[i] = act0[4+i] + mi*(0.02f*zi);
            lpacc += mi*(LPC - 0.5f*zi*zi);
        }
        *(fx4*)(sampled + base0 + 4) = sm;
        #pragma unroll
        for (int i = 0; i < 4; i++){
            float mi = (float)m10[i], zi = z10[i];
            sm[i] = act1[i] + mi*(0.02f*zi);
            lpacc += mi*(LPC - 0.5f*zi*zi);
        }
        *(fx4*)(sampled + base1) = sm;
        #pragma unroll
        for (int i = 0; i < 4; i++){
            float mi = (float)m11[i], zi = z11[i];
            sm[i] = act1[4+i] + mi*(0.02f*zi);
            lpacc += mi*(LPC - 0.5f*zi*zi);
        }
        *(fx4*)(sampled + base1 + 4) = sm;
    }
    #pragma unroll
    for (int off = 32; off > 0; off >>= 1) lpacc += __shfl_xor(lpacc, off);
    if (l == 0) red[wid] = lpacc;
    __syncthreads();
    if (tid == 0){
        float s = 0.f;
        #pragma unroll
        for (int i = 0; i < 8; i++) s += red[i];
        atomicAdd(logp + b, s);
    }
}

extern "C" void kernel_launch(void* const* d_in, const int* in_sizes, int n_in,
                              void* d_out, int out_size, void* d_ws, size_t ws_size,
                              hipStream_t stream){
    const float* x     = (const float*)d_in[0];
    const float* adj   = (const float*)d_in[1];
    const int*   masks = (const int*)  d_in[2];
    const float* noise = (const float*)d_in[3];
    const float* We1   = (const float*)d_in[4];
    const float* be1   = (const float*)d_in[5];
    const float* We2   = (const float*)d_in[6];
    const float* be2   = (const float*)d_in[7];
    const float* Wd1   = (const float*)d_in[8];
    const float* bd1   = (const float*)d_in[9];
    const float* Wd2   = (const float*)d_in[10];
    const float* bd2   = (const float*)d_in[11];

    float* dec     = (float*)d_out;
    float* sampled = dec + (size_t)B_*NN*FF;
    float* logp    = sampled + (size_t)B_*NN*FF;
    // dec region (exactly 134,217,728 B) doubles as bf16-adj scratch until k_dec
    unsigned short* adjb = (unsigned short*)d_out;
    unsigned short* bufA = (unsigned short*)d_ws;              // 4 MB each
    unsigned short* bufB = bufA + (size_t)B_*32*NN;

    hipMemsetAsync(logp, 0, B_*sizeof(float), stream);
    k_xw1<<<dim3(8, B_), 256, 0, stream>>>(x, We1, bufA);                              // u1
    k_adjmm<1,0><<<dim3(8, B_), 256, 0, stream>>>(adj, nullptr, adjb, bufA, be1, 30, 1, bufB); // h1 (+cvt)
    k_tiny<30,18,false><<<dim3(4, B_), 256, 0, stream>>>(bufB, We2, nullptr, bufA);    // u2
    k_adjmm<0,0><<<dim3(8, B_), 256, 0, stream>>>(nullptr, adjb, nullptr, bufA, be2, 18, 0, bufB); // enc
    k_adjmm<0,0><<<dim3(8, B_), 256, 0, stream>>>(nullptr, adjb, nullptr, bufB, nullptr, 0, 0, bufA); // v1
    k_tiny<18,30,true><<<dim3(4, B_), 256, 0, stream>>>(bufA, Wd1, bd1, bufB);         // h2
    k_adjmm<0,1><<<dim3(8, B_), 256, 0, stream>>>(nullptr, adjb, nullptr, bufB, nullptr, 0, 0, bufA); // v2 row-major
    k_dec<<<B_*NN/32, 512, 0, stream>>>(bufA, Wd2, bd2, masks, noise, dec, sampled, logp);
}